// Round 11
// baseline (29.024 us; speedup 1.0000x reference)
//
#include <hip/hip_runtime.h>
#include <stdint.h>
#include <math.h>

// ---------------------------------------------------------------------------
// SubsetItems, round 11: bit-exact math (absmax 0.0 r1-r10). TWO dispatches:
//   k1 noise         -> packed 64-bit total-order keys; zeroes done[8]
//   k2 rank_finalize -> r7 sort+binsearch rank; partials via SYSTEM-scope
//                       relaxed stores (r5-proven, no wbl2); syncthreads
//                       vmcnt drain; agent atomicAdd(done[row]); last block
//                       per row: parallel readback with global_load_dwordx4
//                       sc0 sc1 (MALL-bypass), packed byte-pair accumulate,
//                       scatter idx+weight.
// Model: node boundary ~4us (runtime wbinv) -> cut a node; finalize becomes
// an in-kernel ~1.5us tail instead of a 5.5us latency-bound third kernel.
// ---------------------------------------------------------------------------

#define RANK_G 64
#define JCHUNK 64
#define IPT    16

typedef __attribute__((ext_vector_type(4))) unsigned int u32x4;

struct TF2 { uint32_t a, b; };

__host__ __device__ inline TF2 threefry2x32(uint32_t k0, uint32_t k1,
                                            uint32_t x0, uint32_t x1) {
  const uint32_t ks2 = k0 ^ k1 ^ 0x1BD11BDAu;
#define TF_ROT(v, d) (uint32_t)(((v) << (d)) | ((v) >> (32 - (d))))
#define TF_RND(r) do { x0 += x1; x1 = TF_ROT(x1, r); x1 ^= x0; } while (0)
  x0 += k0; x1 += k1;
  TF_RND(13); TF_RND(15); TF_RND(26); TF_RND(6);
  x0 += k1; x1 += ks2 + 1u;
  TF_RND(17); TF_RND(29); TF_RND(16); TF_RND(24);
  x0 += ks2; x1 += k0 + 2u;
  TF_RND(13); TF_RND(15); TF_RND(26); TF_RND(6);
  x0 += k0; x1 += k1 + 3u;
  TF_RND(17); TF_RND(29); TF_RND(16); TF_RND(24);
  x0 += k1; x1 += ks2 + 4u;
  TF_RND(13); TF_RND(15); TF_RND(26); TF_RND(6);
  x0 += ks2; x1 += k0 + 5u;
#undef TF_RND
#undef TF_ROT
  return {x0, x1};
}

__host__ __device__ __forceinline__ uint32_t random_bits_at(uint32_t ka, uint32_t kb,
                                                            uint32_t idx) {
  TF2 r = threefry2x32(ka, kb, 0u, idx);
  return r.a ^ r.b;
}

// XLA/CHLO ErfInv f32 (bit-exact, verified r1-r10).
__device__ __forceinline__ float erfinv_f32_xla(float x) {
  float xx = __fmul_rn(x, x);
  float v  = -xx;
  float w;
  if (fabsf(v) < 1e-4f) {
    float t = __fmul_rn(__fadd_rn(__fmul_rn(-0.5f, v), 1.0f), v);
    w = -t;
  } else {
    float t = __fadd_rn(v, 1.0f);
    w = -(float)log((double)t);
  }
  float p;
  if (w < 5.0f) {
    float ww = __fadd_rn(w, -2.5f);
    p = 2.81022636e-08f;
    p = __fadd_rn( 3.43273939e-07f, __fmul_rn(p, ww));
    p = __fadd_rn(-3.5233877e-06f,  __fmul_rn(p, ww));
    p = __fadd_rn(-4.39150654e-06f, __fmul_rn(p, ww));
    p = __fadd_rn( 0.00021858087f,  __fmul_rn(p, ww));
    p = __fadd_rn(-0.00125372503f,  __fmul_rn(p, ww));
    p = __fadd_rn(-0.00417768164f,  __fmul_rn(p, ww));
    p = __fadd_rn( 0.246640727f,    __fmul_rn(p, ww));
    p = __fadd_rn( 1.50140941f,     __fmul_rn(p, ww));
  } else {
    float ww = __fadd_rn(__fsqrt_rn(w), -3.0f);
    p = -0.000200214257f;
    p = __fadd_rn( 0.000100950558f, __fmul_rn(p, ww));
    p = __fadd_rn( 0.00134934322f,  __fmul_rn(p, ww));
    p = __fadd_rn(-0.00367342844f,  __fmul_rn(p, ww));
    p = __fadd_rn( 0.00573950773f,  __fmul_rn(p, ww));
    p = __fadd_rn(-0.0076224613f,   __fmul_rn(p, ww));
    p = __fadd_rn( 0.00943887047f,  __fmul_rn(p, ww));
    p = __fadd_rn( 1.00167406f,     __fmul_rn(p, ww));
    p = __fadd_rn( 2.83297682f,     __fmul_rn(p, ww));
  }
  return __fmul_rn(p, x);
}

// Kernel 1: x_noised -> packed 64-bit total-order key; zero done[].
__global__ __launch_bounds__(256)
void noise_kernel(const float* __restrict__ scores, uint64_t* __restrict__ k64,
                  uint32_t* __restrict__ done,
                  uint32_t k1a, uint32_t k1b, uint32_t k3a, uint32_t k3b,
                  uint32_t rowmask) {
  int e = blockIdx.x * 256 + threadIdx.x;   // 32768
  if (e < 8) done[e] = 0u;                  // visible to k2 via node boundary
  int b = e >> 12;

  uint32_t mbits = random_bits_at(k1a, k1b, (uint32_t)e);
  bool mask = ((mbits >> 9) <= 838860u) && ((rowmask >> b) & 1u);

  float s  = scores[e];
  float sf = scores[32767 - e];
  float v  = mask ? fmaxf(s, sf) : s;
  float x  = fminf(fmaxf(v, -1.0f), 1.0f);

  uint32_t nbits = random_bits_at(k3a, k3b, (uint32_t)e);
  float f   = __uint_as_float((nbits >> 9) | 0x3f800000u);
  float f01 = __fadd_rn(f, -1.0f);
  const float lo = __uint_as_float(0xBF7FFFFFu);
  float u = __fadd_rn(__fmul_rn(f01, 2.0f), lo);
  u = fmaxf(lo, u);
  float p    = erfinv_f32_xla(u);
  float nrm  = __fmul_rn(__uint_as_float(0x3FB504F3u), p);
  float nois = __fmul_rn(nrm, 0.0009765625f);
  float xnv  = __fadd_rn(x, nois);

  uint32_t ub = __float_as_uint(xnv);
  uint32_t tk = (ub & 0x80000000u) ? ~ub : (ub | 0x80000000u);
  k64[e] = ((uint64_t)tk << 32) | (uint32_t)(e & 4095);
}

// Kernel 2: rank (sort + step-major lower_bound) + fence-free handoff +
// last-block-per-row parallel MALL readback finalize.
// partial word (row,g,q,tt) packs counts of i = (4q+b)*256+tt in byte b.
__global__ __launch_bounds__(256)
void rank_finalize_kernel(const uint64_t* __restrict__ k64,
                          uint32_t* __restrict__ partial,
                          uint32_t* __restrict__ done,
                          float* __restrict__ out) {
  __shared__ uint64_t jraw[JCHUNK];
  __shared__ uint64_t jsrt[JCHUNK];
  __shared__ int slast;
  int row = blockIdx.x >> 6;              // /RANK_G
  int g   = blockIdx.x & (RANK_G - 1);
  const uint64_t* rk = k64 + row * 4096;
  int t = threadIdx.x;

  // i-keys (independent global loads overlap the sort)
  uint64_t ki[IPT];
#pragma unroll
  for (int m = 0; m < IPT; ++m) ki[m] = rk[m * 256 + t];

  if (t < JCHUNK) jraw[t] = rk[g * JCHUNK + t];
  __syncthreads();
  if (t < JCHUNK) {
    uint64_t kt = jraw[t];
    int r = 0;
#pragma unroll 8
    for (int u = 0; u < JCHUNK; ++u) r += (int)(jraw[u] < kt);
    jsrt[r] = kt;                         // keys unique -> exact ranks
  }
  __syncthreads();

  // step-major branchless lower_bound: pos[m] = #{j in chunk : key_j < ki[m]}
  int pos[IPT];
#pragma unroll
  for (int m = 0; m < IPT; ++m) pos[m] = 0;

  const int offs[7] = {31, 15, 7, 3, 1, 0, 0};
  const int incs[7] = {32, 16, 8, 4, 2, 1, 1};
#pragma unroll
  for (int s = 0; s < 7; ++s) {
    uint64_t v[IPT];
#pragma unroll
    for (int m = 0; m < IPT; ++m) v[m] = jsrt[pos[m] + offs[s]];
#pragma unroll
    for (int m = 0; m < IPT; ++m) pos[m] += (v[m] < ki[m]) ? incs[s] : 0;
  }

  // write-through packed partials (SYSTEM scope: at MALL, no stale L2 copies)
  uint32_t* pw = partial + (row * RANK_G + g) * 1024;
#pragma unroll
  for (int q = 0; q < 4; ++q) {
    uint32_t w = (uint32_t)pos[4 * q]
               | ((uint32_t)pos[4 * q + 1] << 8)
               | ((uint32_t)pos[4 * q + 2] << 16)
               | ((uint32_t)pos[4 * q + 3] << 24);
    __hip_atomic_store(&pw[q * 256 + t], w, __ATOMIC_RELAXED,
                       __HIP_MEMORY_SCOPE_SYSTEM);
  }

  __syncthreads();   // s_waitcnt vmcnt(0): all waves' stores reached MALL
  if (t == 0)
    slast = (__hip_atomic_fetch_add(&done[row], 1u, __ATOMIC_RELAXED,
                                    __HIP_MEMORY_SCOPE_AGENT)
             == (uint32_t)(RANK_G - 1));
  __syncthreads();
  if (!slast) return;

  // --- last block of this row: parallel MALL readback + scatter ---
  // thread t: qq = t>>6, u = t&63 -> columns tt = 4u..4u+3 of q-group qq.
  int qq = t >> 6, u = t & 63;
  uint32_t vbase = (uint32_t)(qq * 256 + u * 4) * 4u;   // byte offset in row
  uint64_t sbase = (uint64_t)(uintptr_t)(partial + row * RANK_G * 1024);

  uint32_t accLo[4] = {0, 0, 0, 0};   // byte0 + byte2<<16 sums (16-bit fields)
  uint32_t accHi[4] = {0, 0, 0, 0};   // byte1 + byte3<<16 sums

  u32x4 d[16];
#pragma unroll
  for (int bb = 0; bb < 4; ++bb) {    // 4 batches x 16 loads in flight
#pragma unroll
    for (int l = 0; l < 16; ++l) {
      uint32_t vo = vbase + (uint32_t)(bb * 16 + l) * 4096u;  // g stride
      asm volatile("global_load_dwordx4 %0, %1, %2 sc0 sc1"
                   : "=v"(d[l]) : "v"(vo), "s"(sbase));
    }
    asm volatile("s_waitcnt vmcnt(0)");
    __builtin_amdgcn_sched_barrier(0);
#pragma unroll
    for (int l = 0; l < 16; ++l) {
      accLo[0] += d[l].x & 0x00FF00FFu; accHi[0] += (d[l].x >> 8) & 0x00FF00FFu;
      accLo[1] += d[l].y & 0x00FF00FFu; accHi[1] += (d[l].y >> 8) & 0x00FF00FFu;
      accLo[2] += d[l].z & 0x00FF00FFu; accHi[2] += (d[l].z >> 8) & 0x00FF00FFu;
      accLo[3] += d[l].w & 0x00FF00FFu; accHi[3] += (d[l].w >> 8) & 0x00FF00FFu;
    }
  }

#pragma unroll
  for (int jj = 0; jj < 4; ++jj) {
    int tt = u * 4 + jj;
    int rs[4] = { (int)(accLo[jj] & 0xFFFFu),   // byte 0
                  (int)(accHi[jj] & 0xFFFFu),   // byte 1
                  (int)(accLo[jj] >> 16),       // byte 2
                  (int)(accHi[jj] >> 16) };     // byte 3
#pragma unroll
    for (int b = 0; b < 4; ++b) {
      int r = rs[b];
      if (r >= 2048) {
        int jo = r - 2048;
        int i = (4 * qq + b) * 256 + tt;
        out[row * 2048 + jo] = (float)i;
        out[16384 + row * 2048 + jo] = fminf(__fdiv_rn((float)jo, 204.8f), 1.0f);
      }
    }
  }
}

extern "C" void kernel_launch(void* const* d_in, const int* in_sizes, int n_in,
                              void* d_out, int out_size, void* d_ws, size_t ws_size,
                              hipStream_t stream) {
  const float* scores = (const float*)d_in[0];
  float* out = (float*)d_out;

  uint64_t* k64     = (uint64_t*)d_ws;                          // 256 KB
  uint32_t* partial = (uint32_t*)((uint8_t*)d_ws + 32768 * 8);  // 2 MB
  uint32_t* done    = (uint32_t*)((uint8_t*)d_ws + 32768 * 8 + 8 * RANK_G * 1024 * 4);

  // split(key(42), 3), partitionable layout (verified r1)
  TF2 K1 = threefry2x32(0u, 42u, 0u, 0u);
  TF2 K2 = threefry2x32(0u, 42u, 0u, 1u);
  TF2 K3 = threefry2x32(0u, 42u, 0u, 2u);

  // batch_mask rows on host: uniform(k2,(8,1)) < 0.75
  uint32_t rowmask = 0;
  for (uint32_t b = 0; b < 8; ++b) {
    uint32_t bits = random_bits_at(K2.a, K2.b, b);
    if ((bits >> 9) < 6291456u) rowmask |= (1u << b);
  }

  noise_kernel<<<128, 256, 0, stream>>>(scores, k64, done,
                                        K1.a, K1.b, K3.a, K3.b, rowmask);
  rank_finalize_kernel<<<8 * RANK_G, 256, 0, stream>>>(k64, partial, done, out);
}

// Round 12
// 18.530 us; speedup vs baseline: 1.5664x; 1.5664x over previous
//
#include <hip/hip_runtime.h>
#include <stdint.h>
#include <math.h>

// ---------------------------------------------------------------------------
// SubsetItems, round 12: bit-exact math (absmax 0.0 r1-r11). 3 dispatches —
// r7 skeleton (fusion attempts r4/r5/r8/r11 all >=8us worse: cross-block
// handoff at the coherence point beats a plain node boundary, never fuse).
// Changes vs r7:
//   - finalize re-grid 32 -> 256 blocks: 32 words x 8 g-groups per block,
//     8-deep load chains instead of 64-deep, LDS tree reduce (exact).
//   - noise re-grid 128x256 -> 256x128: same 512 waves on all 256 CUs.
//   k1 noise    -> packed 64-bit total-order keys (tk<<32 | col)
//   k2 rank     -> per-block j-chunk sort + step-major lower_bound, u8x4 pack
//   k3 finalize -> g-split partial sums + LDS reduce, scatter idx+weight
// ---------------------------------------------------------------------------

#define RANK_G 64
#define JCHUNK 64
#define IPT    16

struct TF2 { uint32_t a, b; };

__host__ __device__ inline TF2 threefry2x32(uint32_t k0, uint32_t k1,
                                            uint32_t x0, uint32_t x1) {
  const uint32_t ks2 = k0 ^ k1 ^ 0x1BD11BDAu;
#define TF_ROT(v, d) (uint32_t)(((v) << (d)) | ((v) >> (32 - (d))))
#define TF_RND(r) do { x0 += x1; x1 = TF_ROT(x1, r); x1 ^= x0; } while (0)
  x0 += k0; x1 += k1;
  TF_RND(13); TF_RND(15); TF_RND(26); TF_RND(6);
  x0 += k1; x1 += ks2 + 1u;
  TF_RND(17); TF_RND(29); TF_RND(16); TF_RND(24);
  x0 += ks2; x1 += k0 + 2u;
  TF_RND(13); TF_RND(15); TF_RND(26); TF_RND(6);
  x0 += k0; x1 += k1 + 3u;
  TF_RND(17); TF_RND(29); TF_RND(16); TF_RND(24);
  x0 += k1; x1 += ks2 + 4u;
  TF_RND(13); TF_RND(15); TF_RND(26); TF_RND(6);
  x0 += ks2; x1 += k0 + 5u;
#undef TF_RND
#undef TF_ROT
  return {x0, x1};
}

__host__ __device__ __forceinline__ uint32_t random_bits_at(uint32_t ka, uint32_t kb,
                                                            uint32_t idx) {
  TF2 r = threefry2x32(ka, kb, 0u, idx);
  return r.a ^ r.b;
}

// XLA/CHLO ErfInv f32 (bit-exact, verified r1-r11).
__device__ __forceinline__ float erfinv_f32_xla(float x) {
  float xx = __fmul_rn(x, x);
  float v  = -xx;
  float w;
  if (fabsf(v) < 1e-4f) {
    float t = __fmul_rn(__fadd_rn(__fmul_rn(-0.5f, v), 1.0f), v);
    w = -t;
  } else {
    float t = __fadd_rn(v, 1.0f);
    w = -(float)log((double)t);
  }
  float p;
  if (w < 5.0f) {
    float ww = __fadd_rn(w, -2.5f);
    p = 2.81022636e-08f;
    p = __fadd_rn( 3.43273939e-07f, __fmul_rn(p, ww));
    p = __fadd_rn(-3.5233877e-06f,  __fmul_rn(p, ww));
    p = __fadd_rn(-4.39150654e-06f, __fmul_rn(p, ww));
    p = __fadd_rn( 0.00021858087f,  __fmul_rn(p, ww));
    p = __fadd_rn(-0.00125372503f,  __fmul_rn(p, ww));
    p = __fadd_rn(-0.00417768164f,  __fmul_rn(p, ww));
    p = __fadd_rn( 0.246640727f,    __fmul_rn(p, ww));
    p = __fadd_rn( 1.50140941f,     __fmul_rn(p, ww));
  } else {
    float ww = __fadd_rn(__fsqrt_rn(w), -3.0f);
    p = -0.000200214257f;
    p = __fadd_rn( 0.000100950558f, __fmul_rn(p, ww));
    p = __fadd_rn( 0.00134934322f,  __fmul_rn(p, ww));
    p = __fadd_rn(-0.00367342844f,  __fmul_rn(p, ww));
    p = __fadd_rn( 0.00573950773f,  __fmul_rn(p, ww));
    p = __fadd_rn(-0.0076224613f,   __fmul_rn(p, ww));
    p = __fadd_rn( 0.00943887047f,  __fmul_rn(p, ww));
    p = __fadd_rn( 1.00167406f,     __fmul_rn(p, ww));
    p = __fadd_rn( 2.83297682f,     __fmul_rn(p, ww));
  }
  return __fmul_rn(p, x);
}

// Kernel 1: x_noised -> packed 64-bit total-order key. 256 blocks x 128.
__global__ __launch_bounds__(128)
void noise_kernel(const float* __restrict__ scores, uint64_t* __restrict__ k64,
                  uint32_t k1a, uint32_t k1b, uint32_t k3a, uint32_t k3b,
                  uint32_t rowmask) {
  int e = blockIdx.x * 128 + threadIdx.x;   // 32768
  int b = e >> 12;

  uint32_t mbits = random_bits_at(k1a, k1b, (uint32_t)e);
  bool mask = ((mbits >> 9) <= 838860u) && ((rowmask >> b) & 1u);

  float s  = scores[e];
  float sf = scores[32767 - e];
  float v  = mask ? fmaxf(s, sf) : s;
  float x  = fminf(fmaxf(v, -1.0f), 1.0f);

  uint32_t nbits = random_bits_at(k3a, k3b, (uint32_t)e);
  float f   = __uint_as_float((nbits >> 9) | 0x3f800000u);
  float f01 = __fadd_rn(f, -1.0f);
  const float lo = __uint_as_float(0xBF7FFFFFu);
  float u = __fadd_rn(__fmul_rn(f01, 2.0f), lo);
  u = fmaxf(lo, u);
  float p    = erfinv_f32_xla(u);
  float nrm  = __fmul_rn(__uint_as_float(0x3FB504F3u), p);
  float nois = __fmul_rn(nrm, 0.0009765625f);
  float xnv  = __fadd_rn(x, nois);

  uint32_t ub = __float_as_uint(xnv);
  uint32_t tk = (ub & 0x80000000u) ? ~ub : (ub | 0x80000000u);
  k64[e] = ((uint64_t)tk << 32) | (uint32_t)(e & 4095);
}

// Kernel 2: partial ranks via per-block j-chunk sort + STEP-MAJOR lower_bound.
// partial word (row,g,q,tt) packs counts of i = (4q+b)*256+tt in byte b.
__global__ __launch_bounds__(256)
void rank_kernel(const uint64_t* __restrict__ k64,
                 uint32_t* __restrict__ partial) {
  __shared__ uint64_t jraw[JCHUNK];
  __shared__ uint64_t jsrt[JCHUNK];
  int row = blockIdx.x >> 6;              // /RANK_G
  int g   = blockIdx.x & (RANK_G - 1);
  const uint64_t* rk = k64 + row * 4096;
  int t = threadIdx.x;

  // i-keys (independent global loads overlap the sort)
  uint64_t ki[IPT];
#pragma unroll
  for (int m = 0; m < IPT; ++m) ki[m] = rk[m * 256 + t];

  if (t < JCHUNK) jraw[t] = rk[g * JCHUNK + t];
  __syncthreads();
  if (t < JCHUNK) {
    uint64_t kt = jraw[t];
    int r = 0;
#pragma unroll 8
    for (int u = 0; u < JCHUNK; ++u) r += (int)(jraw[u] < kt);
    jsrt[r] = kt;                         // keys unique -> exact ranks
  }
  __syncthreads();

  // step-major branchless lower_bound: pos[m] = #{j in chunk : key_j < ki[m]}
  int pos[IPT];
#pragma unroll
  for (int m = 0; m < IPT; ++m) pos[m] = 0;

  const int offs[7] = {31, 15, 7, 3, 1, 0, 0};
  const int incs[7] = {32, 16, 8, 4, 2, 1, 1};
#pragma unroll
  for (int s = 0; s < 7; ++s) {
    uint64_t v[IPT];
#pragma unroll
    for (int m = 0; m < IPT; ++m) v[m] = jsrt[pos[m] + offs[s]];
#pragma unroll
    for (int m = 0; m < IPT; ++m) pos[m] += (v[m] < ki[m]) ? incs[s] : 0;
  }

  uint32_t* pw = partial + (row * RANK_G + g) * 1024;
#pragma unroll
  for (int q = 0; q < 4; ++q) {
    uint32_t w = (uint32_t)pos[4 * q]
               | ((uint32_t)pos[4 * q + 1] << 8)
               | ((uint32_t)pos[4 * q + 2] << 16)
               | ((uint32_t)pos[4 * q + 3] << 24);
    pw[q * 256 + t] = w;
  }
}

// Kernel 3: 256 blocks. Block handles 32 word-columns x 8 g-groups.
// Thread (wl = t&31, gg = t>>5): sums its column over g = gg*8..gg*8+7 in
// packed 16-bit fields (max 8*64=512, exact), LDS tree over the 8 g-groups,
// then threads wl<32 extract 4 byte-sums and scatter idx+weight.
__global__ __launch_bounds__(256)
void finalize_kernel(const uint32_t* __restrict__ partial,
                     float* __restrict__ out) {
  __shared__ uint32_t ldsLo[8][32];
  __shared__ uint32_t ldsHi[8][32];
  int t  = threadIdx.x;
  int wl = t & 31;
  int gg = t >> 5;                         // 0..7
  int c   = blockIdx.x * 32 + wl;          // word-column 0..8191
  int row = c >> 10;
  int k   = c & 1023;

  const uint32_t* prow = partial + (row * RANK_G + gg * 8) * 1024 + k;
  uint32_t lo = 0, hi = 0;
#pragma unroll
  for (int gi = 0; gi < 8; ++gi) {
    uint32_t w = prow[gi * 1024];
    lo += w & 0x00FF00FFu;
    hi += (w >> 8) & 0x00FF00FFu;
  }
  ldsLo[gg][wl] = lo;
  ldsHi[gg][wl] = hi;
  __syncthreads();

  if (t < 32) {                            // wl == t
    uint32_t accLo = 0, accHi = 0;
#pragma unroll
    for (int g2 = 0; g2 < 8; ++g2) { accLo += ldsLo[g2][t]; accHi += ldsHi[g2][t]; }
    int q = k >> 8, tt = k & 255;
    int rs[4] = { (int)(accLo & 0xFFFFu),  // byte 0
                  (int)(accHi & 0xFFFFu),  // byte 1
                  (int)(accLo >> 16),      // byte 2
                  (int)(accHi >> 16) };    // byte 3
#pragma unroll
    for (int b = 0; b < 4; ++b) {
      int r = rs[b];
      if (r >= 2048) {
        int j = r - 2048;
        int i = (4 * q + b) * 256 + tt;
        out[row * 2048 + j] = (float)i;
        out[16384 + row * 2048 + j] = fminf(__fdiv_rn((float)j, 204.8f), 1.0f);
      }
    }
  }
}

extern "C" void kernel_launch(void* const* d_in, const int* in_sizes, int n_in,
                              void* d_out, int out_size, void* d_ws, size_t ws_size,
                              hipStream_t stream) {
  const float* scores = (const float*)d_in[0];
  float* out = (float*)d_out;

  uint64_t* k64     = (uint64_t*)d_ws;                          // 256 KB
  uint32_t* partial = (uint32_t*)((uint8_t*)d_ws + 32768 * 8);  // 2 MB

  // split(key(42), 3), partitionable layout (verified r1)
  TF2 K1 = threefry2x32(0u, 42u, 0u, 0u);
  TF2 K2 = threefry2x32(0u, 42u, 0u, 1u);
  TF2 K3 = threefry2x32(0u, 42u, 0u, 2u);

  // batch_mask rows on host: uniform(k2,(8,1)) < 0.75
  uint32_t rowmask = 0;
  for (uint32_t b = 0; b < 8; ++b) {
    uint32_t bits = random_bits_at(K2.a, K2.b, b);
    if ((bits >> 9) < 6291456u) rowmask |= (1u << b);
  }

  noise_kernel<<<256, 128, 0, stream>>>(scores, k64,
                                        K1.a, K1.b, K3.a, K3.b, rowmask);
  rank_kernel<<<8 * RANK_G, 256, 0, stream>>>(k64, partial);
  finalize_kernel<<<256, 256, 0, stream>>>(partial, out);
}

// Round 13
// 17.868 us; speedup vs baseline: 1.6244x; 1.0371x over previous
//
#include <hip/hip_runtime.h>
#include <stdint.h>
#include <math.h>

// ---------------------------------------------------------------------------
// SubsetItems, round 13: bit-exact math (absmax 0.0 r1-r12). 3 dispatches
// (r4/r5/r8/r11: fusion always >=8us worse; node overhead ~1us — keep nodes).
// Changes vs r12 (18.5us):
//   - JCHUNK 128 / RANK_G 32: partial matrix 2MB -> 1MB (counts <=128 fit u8),
//     finalize chains 8 -> 4 deep, rank 256 blocks x 512 thr (same 2048 waves)
//   - rank i-keys remapped i=8t+m, loaded as 4x dwordx4 (64B/lane contiguous);
//     partial word W packs i=4W+b, written as one coalesced uint2 per thread
//   - lower_bound extended to 8 steps (n=128)
//   k1 noise    -> packed 64-bit total-order keys (tk<<32 | col)
//   k2 rank     -> per-block 128-key sort + step-major lower_bound, u8x4 pack
//   k3 finalize -> 4-deep g-sums + LDS tree, scatter idx+weight
// ---------------------------------------------------------------------------

#define RANK_G 32
#define JCHUNK 128    // per-(i,g) count <= 128, fits u8
#define IPT    8      // i-keys per thread (512-thread rank blocks)

struct TF2 { uint32_t a, b; };

__host__ __device__ inline TF2 threefry2x32(uint32_t k0, uint32_t k1,
                                            uint32_t x0, uint32_t x1) {
  const uint32_t ks2 = k0 ^ k1 ^ 0x1BD11BDAu;
#define TF_ROT(v, d) (uint32_t)(((v) << (d)) | ((v) >> (32 - (d))))
#define TF_RND(r) do { x0 += x1; x1 = TF_ROT(x1, r); x1 ^= x0; } while (0)
  x0 += k0; x1 += k1;
  TF_RND(13); TF_RND(15); TF_RND(26); TF_RND(6);
  x0 += k1; x1 += ks2 + 1u;
  TF_RND(17); TF_RND(29); TF_RND(16); TF_RND(24);
  x0 += ks2; x1 += k0 + 2u;
  TF_RND(13); TF_RND(15); TF_RND(26); TF_RND(6);
  x0 += k0; x1 += k1 + 3u;
  TF_RND(17); TF_RND(29); TF_RND(16); TF_RND(24);
  x0 += k1; x1 += ks2 + 4u;
  TF_RND(13); TF_RND(15); TF_RND(26); TF_RND(6);
  x0 += ks2; x1 += k0 + 5u;
#undef TF_RND
#undef TF_ROT
  return {x0, x1};
}

__host__ __device__ __forceinline__ uint32_t random_bits_at(uint32_t ka, uint32_t kb,
                                                            uint32_t idx) {
  TF2 r = threefry2x32(ka, kb, 0u, idx);
  return r.a ^ r.b;
}

// XLA/CHLO ErfInv f32 (bit-exact, verified r1-r12).
__device__ __forceinline__ float erfinv_f32_xla(float x) {
  float xx = __fmul_rn(x, x);
  float v  = -xx;
  float w;
  if (fabsf(v) < 1e-4f) {
    float t = __fmul_rn(__fadd_rn(__fmul_rn(-0.5f, v), 1.0f), v);
    w = -t;
  } else {
    float t = __fadd_rn(v, 1.0f);
    w = -(float)log((double)t);
  }
  float p;
  if (w < 5.0f) {
    float ww = __fadd_rn(w, -2.5f);
    p = 2.81022636e-08f;
    p = __fadd_rn( 3.43273939e-07f, __fmul_rn(p, ww));
    p = __fadd_rn(-3.5233877e-06f,  __fmul_rn(p, ww));
    p = __fadd_rn(-4.39150654e-06f, __fmul_rn(p, ww));
    p = __fadd_rn( 0.00021858087f,  __fmul_rn(p, ww));
    p = __fadd_rn(-0.00125372503f,  __fmul_rn(p, ww));
    p = __fadd_rn(-0.00417768164f,  __fmul_rn(p, ww));
    p = __fadd_rn( 0.246640727f,    __fmul_rn(p, ww));
    p = __fadd_rn( 1.50140941f,     __fmul_rn(p, ww));
  } else {
    float ww = __fadd_rn(__fsqrt_rn(w), -3.0f);
    p = -0.000200214257f;
    p = __fadd_rn( 0.000100950558f, __fmul_rn(p, ww));
    p = __fadd_rn( 0.00134934322f,  __fmul_rn(p, ww));
    p = __fadd_rn(-0.00367342844f,  __fmul_rn(p, ww));
    p = __fadd_rn( 0.00573950773f,  __fmul_rn(p, ww));
    p = __fadd_rn(-0.0076224613f,   __fmul_rn(p, ww));
    p = __fadd_rn( 0.00943887047f,  __fmul_rn(p, ww));
    p = __fadd_rn( 1.00167406f,     __fmul_rn(p, ww));
    p = __fadd_rn( 2.83297682f,     __fmul_rn(p, ww));
  }
  return __fmul_rn(p, x);
}

// Kernel 1: x_noised -> packed 64-bit total-order key. 256 blocks x 128.
__global__ __launch_bounds__(128)
void noise_kernel(const float* __restrict__ scores, uint64_t* __restrict__ k64,
                  uint32_t k1a, uint32_t k1b, uint32_t k3a, uint32_t k3b,
                  uint32_t rowmask) {
  int e = blockIdx.x * 128 + threadIdx.x;   // 32768
  int b = e >> 12;

  uint32_t mbits = random_bits_at(k1a, k1b, (uint32_t)e);
  bool mask = ((mbits >> 9) <= 838860u) && ((rowmask >> b) & 1u);

  float s  = scores[e];
  float sf = scores[32767 - e];
  float v  = mask ? fmaxf(s, sf) : s;
  float x  = fminf(fmaxf(v, -1.0f), 1.0f);

  uint32_t nbits = random_bits_at(k3a, k3b, (uint32_t)e);
  float f   = __uint_as_float((nbits >> 9) | 0x3f800000u);
  float f01 = __fadd_rn(f, -1.0f);
  const float lo = __uint_as_float(0xBF7FFFFFu);
  float u = __fadd_rn(__fmul_rn(f01, 2.0f), lo);
  u = fmaxf(lo, u);
  float p    = erfinv_f32_xla(u);
  float nrm  = __fmul_rn(__uint_as_float(0x3FB504F3u), p);
  float nois = __fmul_rn(nrm, 0.0009765625f);
  float xnv  = __fadd_rn(x, nois);

  uint32_t ub = __float_as_uint(xnv);
  uint32_t tk = (ub & 0x80000000u) ? ~ub : (ub | 0x80000000u);
  k64[e] = ((uint64_t)tk << 32) | (uint32_t)(e & 4095);
}

// Kernel 2: 256 blocks x 512 threads. Block (row, g): sort its 128-key
// j-chunk, then step-major lower_bound for 8 i-keys/thread (i = 8t+m,
// loaded as 4x dwordx4). Partial word W = 2t+q packs counts of i = 4W+b.
__global__ __launch_bounds__(512)
void rank_kernel(const uint64_t* __restrict__ k64,
                 uint32_t* __restrict__ partial) {
  __shared__ uint64_t jraw[JCHUNK];
  __shared__ uint64_t jsrt[JCHUNK];
  int row = blockIdx.x >> 5;              // /RANK_G
  int g   = blockIdx.x & (RANK_G - 1);
  const uint64_t* rk = k64 + row * 4096;
  int t = threadIdx.x;                    // 0..511

  // i-keys: i = 8t+m, 4 contiguous 16B loads per thread (issued before sort)
  uint64_t ki[IPT];
  {
    const ulonglong2* p = (const ulonglong2*)(rk + t * 8);
    ulonglong2 a = p[0], b2 = p[1], c = p[2], d = p[3];
    ki[0] = a.x; ki[1] = a.y; ki[2] = b2.x; ki[3] = b2.y;
    ki[4] = c.x; ki[5] = c.y; ki[6] = d.x;  ki[7] = d.y;
  }

  if (t < JCHUNK) jraw[t] = rk[g * JCHUNK + t];
  __syncthreads();
  if (t < JCHUNK) {
    uint64_t kt = jraw[t];
    int r = 0;
#pragma unroll 8
    for (int u = 0; u < JCHUNK; ++u) r += (int)(jraw[u] < kt);
    jsrt[r] = kt;                         // keys unique -> exact ranks
  }
  __syncthreads();

  // step-major branchless lower_bound over 128 sorted keys (8 steps)
  int pos[IPT];
#pragma unroll
  for (int m = 0; m < IPT; ++m) pos[m] = 0;

  const int offs[8] = {63, 31, 15, 7, 3, 1, 0, 0};
  const int incs[8] = {64, 32, 16, 8, 4, 2, 1, 1};
#pragma unroll
  for (int s = 0; s < 8; ++s) {
    uint64_t v[IPT];
#pragma unroll
    for (int m = 0; m < IPT; ++m) v[m] = jsrt[pos[m] + offs[s]];
#pragma unroll
    for (int m = 0; m < IPT; ++m) pos[m] += (v[m] < ki[m]) ? incs[s] : 0;
  }

  // pack: word 2t   = counts of i = 8t+0..3   (bytes 0..3)
  //       word 2t+1 = counts of i = 8t+4..7   -> word W holds i = 4W+b
  uint32_t w0 = (uint32_t)pos[0] | ((uint32_t)pos[1] << 8)
              | ((uint32_t)pos[2] << 16) | ((uint32_t)pos[3] << 24);
  uint32_t w1 = (uint32_t)pos[4] | ((uint32_t)pos[5] << 8)
              | ((uint32_t)pos[6] << 16) | ((uint32_t)pos[7] << 24);
  uint2* pw = (uint2*)(partial + (row * RANK_G + g) * 1024);
  pw[t] = make_uint2(w0, w1);             // 8B/lane coalesced
}

// Kernel 3: 256 blocks. Block: 32 word-columns x 8 g-groups (4 g each).
// Thread (wl=t&31, gg=t>>5) sums packed byte-pairs over 4 partials (max
// 4*128=512 per 16-bit field), LDS tree over 8 groups (max 4096), threads
// t<32 extract byte-sums and scatter idx+weight (i = 4w+b).
__global__ __launch_bounds__(256)
void finalize_kernel(const uint32_t* __restrict__ partial,
                     float* __restrict__ out) {
  __shared__ uint32_t ldsLo[8][32];
  __shared__ uint32_t ldsHi[8][32];
  int t  = threadIdx.x;
  int wl = t & 31;
  int gg = t >> 5;                         // 0..7
  int c   = blockIdx.x * 32 + wl;          // word-column 0..8191
  int row = c >> 10;
  int w   = c & 1023;

  const uint32_t* prow = partial + (row * RANK_G + gg * 4) * 1024 + w;
  uint32_t lo = 0, hi = 0;
#pragma unroll
  for (int gi = 0; gi < 4; ++gi) {
    uint32_t x = prow[gi * 1024];
    lo += x & 0x00FF00FFu;
    hi += (x >> 8) & 0x00FF00FFu;
  }
  ldsLo[gg][wl] = lo;
  ldsHi[gg][wl] = hi;
  __syncthreads();

  if (t < 32) {
    int c2  = blockIdx.x * 32 + t;
    int row2 = c2 >> 10;
    int w2   = c2 & 1023;
    uint32_t accLo = 0, accHi = 0;
#pragma unroll
    for (int g2 = 0; g2 < 8; ++g2) { accLo += ldsLo[g2][t]; accHi += ldsHi[g2][t]; }
    int rs[4] = { (int)(accLo & 0xFFFFu),  // byte 0
                  (int)(accHi & 0xFFFFu),  // byte 1
                  (int)(accLo >> 16),      // byte 2
                  (int)(accHi >> 16) };    // byte 3
#pragma unroll
    for (int b = 0; b < 4; ++b) {
      int r = rs[b];
      if (r >= 2048) {
        int j = r - 2048;
        int i = 4 * w2 + b;
        out[row2 * 2048 + j] = (float)i;
        out[16384 + row2 * 2048 + j] = fminf(__fdiv_rn((float)j, 204.8f), 1.0f);
      }
    }
  }
}

extern "C" void kernel_launch(void* const* d_in, const int* in_sizes, int n_in,
                              void* d_out, int out_size, void* d_ws, size_t ws_size,
                              hipStream_t stream) {
  const float* scores = (const float*)d_in[0];
  float* out = (float*)d_out;

  uint64_t* k64     = (uint64_t*)d_ws;                          // 256 KB
  uint32_t* partial = (uint32_t*)((uint8_t*)d_ws + 32768 * 8);  // 1 MB

  // split(key(42), 3), partitionable layout (verified r1)
  TF2 K1 = threefry2x32(0u, 42u, 0u, 0u);
  TF2 K2 = threefry2x32(0u, 42u, 0u, 1u);
  TF2 K3 = threefry2x32(0u, 42u, 0u, 2u);

  // batch_mask rows on host: uniform(k2,(8,1)) < 0.75
  uint32_t rowmask = 0;
  for (uint32_t b = 0; b < 8; ++b) {
    uint32_t bits = random_bits_at(K2.a, K2.b, b);
    if ((bits >> 9) < 6291456u) rowmask |= (1u << b);
  }

  noise_kernel<<<256, 128, 0, stream>>>(scores, k64,
                                        K1.a, K1.b, K3.a, K3.b, rowmask);
  rank_kernel<<<8 * RANK_G, 512, 0, stream>>>(k64, partial);
  finalize_kernel<<<256, 256, 0, stream>>>(partial, out);
}

// Round 14
// 17.775 us; speedup vs baseline: 1.6329x; 1.0052x over previous
//
#include <hip/hip_runtime.h>
#include <stdint.h>
#include <math.h>

// ---------------------------------------------------------------------------
// SubsetItems, round 14: bit-exact math (absmax 0.0 r1-r13). TWO dispatches,
// no cross-block handoff (r4/r5/r8/r11: in-kernel handoff always loses):
//   k1 noise_sort -> per 128-elem chunk: noise keys (exact r13 math), write
//                    unsorted k64, LDS rank-sort chunk, write sorted ksrt.
//   k2 rank_out   -> block (row, i-chunk of 512): stage row's 32 sorted
//                    chunks (32KB) in LDS; per thread: own key from k64,
//                    lower_bound in all 32 chunks (step-major 2x16x8 steps),
//                    rank = sum of positions; rank>=2048 -> scatter directly.
// Removes the 1MB partial matrix, the finalize kernel, and one boundary.
// ---------------------------------------------------------------------------

#define NCHUNK 32     // chunks per row
#define CLEN   128    // chunk length

struct TF2 { uint32_t a, b; };

__host__ __device__ inline TF2 threefry2x32(uint32_t k0, uint32_t k1,
                                            uint32_t x0, uint32_t x1) {
  const uint32_t ks2 = k0 ^ k1 ^ 0x1BD11BDAu;
#define TF_ROT(v, d) (uint32_t)(((v) << (d)) | ((v) >> (32 - (d))))
#define TF_RND(r) do { x0 += x1; x1 = TF_ROT(x1, r); x1 ^= x0; } while (0)
  x0 += k0; x1 += k1;
  TF_RND(13); TF_RND(15); TF_RND(26); TF_RND(6);
  x0 += k1; x1 += ks2 + 1u;
  TF_RND(17); TF_RND(29); TF_RND(16); TF_RND(24);
  x0 += ks2; x1 += k0 + 2u;
  TF_RND(13); TF_RND(15); TF_RND(26); TF_RND(6);
  x0 += k0; x1 += k1 + 3u;
  TF_RND(17); TF_RND(29); TF_RND(16); TF_RND(24);
  x0 += k1; x1 += ks2 + 4u;
  TF_RND(13); TF_RND(15); TF_RND(26); TF_RND(6);
  x0 += ks2; x1 += k0 + 5u;
#undef TF_RND
#undef TF_ROT
  return {x0, x1};
}

__host__ __device__ __forceinline__ uint32_t random_bits_at(uint32_t ka, uint32_t kb,
                                                            uint32_t idx) {
  TF2 r = threefry2x32(ka, kb, 0u, idx);
  return r.a ^ r.b;
}

// XLA/CHLO ErfInv f32 (bit-exact, verified r1-r13).
__device__ __forceinline__ float erfinv_f32_xla(float x) {
  float xx = __fmul_rn(x, x);
  float v  = -xx;
  float w;
  if (fabsf(v) < 1e-4f) {
    float t = __fmul_rn(__fadd_rn(__fmul_rn(-0.5f, v), 1.0f), v);
    w = -t;
  } else {
    float t = __fadd_rn(v, 1.0f);
    w = -(float)log((double)t);
  }
  float p;
  if (w < 5.0f) {
    float ww = __fadd_rn(w, -2.5f);
    p = 2.81022636e-08f;
    p = __fadd_rn( 3.43273939e-07f, __fmul_rn(p, ww));
    p = __fadd_rn(-3.5233877e-06f,  __fmul_rn(p, ww));
    p = __fadd_rn(-4.39150654e-06f, __fmul_rn(p, ww));
    p = __fadd_rn( 0.00021858087f,  __fmul_rn(p, ww));
    p = __fadd_rn(-0.00125372503f,  __fmul_rn(p, ww));
    p = __fadd_rn(-0.00417768164f,  __fmul_rn(p, ww));
    p = __fadd_rn( 0.246640727f,    __fmul_rn(p, ww));
    p = __fadd_rn( 1.50140941f,     __fmul_rn(p, ww));
  } else {
    float ww = __fadd_rn(__fsqrt_rn(w), -3.0f);
    p = -0.000200214257f;
    p = __fadd_rn( 0.000100950558f, __fmul_rn(p, ww));
    p = __fadd_rn( 0.00134934322f,  __fmul_rn(p, ww));
    p = __fadd_rn(-0.00367342844f,  __fmul_rn(p, ww));
    p = __fadd_rn( 0.00573950773f,  __fmul_rn(p, ww));
    p = __fadd_rn(-0.0076224613f,   __fmul_rn(p, ww));
    p = __fadd_rn( 0.00943887047f,  __fmul_rn(p, ww));
    p = __fadd_rn( 1.00167406f,     __fmul_rn(p, ww));
    p = __fadd_rn( 2.83297682f,     __fmul_rn(p, ww));
  }
  return __fmul_rn(p, x);
}

// Kernel 1: noise -> keys; write unsorted k64; LDS rank-sort the block's
// 128-key chunk (keys unique -> exact scatter); write sorted ksrt.
__global__ __launch_bounds__(128)
void noise_sort_kernel(const float* __restrict__ scores,
                       uint64_t* __restrict__ k64,
                       uint64_t* __restrict__ ksrt,
                       uint32_t k1a, uint32_t k1b, uint32_t k3a, uint32_t k3b,
                       uint32_t rowmask) {
  __shared__ uint64_t jraw[CLEN];
  __shared__ uint64_t jsrt[CLEN];
  int t = threadIdx.x;
  int e = blockIdx.x * CLEN + t;            // 32768
  int b = e >> 12;

  uint32_t mbits = random_bits_at(k1a, k1b, (uint32_t)e);
  bool mask = ((mbits >> 9) <= 838860u) && ((rowmask >> b) & 1u);

  float s  = scores[e];
  float sf = scores[32767 - e];
  float v  = mask ? fmaxf(s, sf) : s;
  float x  = fminf(fmaxf(v, -1.0f), 1.0f);

  uint32_t nbits = random_bits_at(k3a, k3b, (uint32_t)e);
  float f   = __uint_as_float((nbits >> 9) | 0x3f800000u);
  float f01 = __fadd_rn(f, -1.0f);
  const float lo = __uint_as_float(0xBF7FFFFFu);
  float u = __fadd_rn(__fmul_rn(f01, 2.0f), lo);
  u = fmaxf(lo, u);
  float p    = erfinv_f32_xla(u);
  float nrm  = __fmul_rn(__uint_as_float(0x3FB504F3u), p);
  float nois = __fmul_rn(nrm, 0.0009765625f);
  float xnv  = __fadd_rn(x, nois);

  uint32_t ub = __float_as_uint(xnv);
  uint32_t tk = (ub & 0x80000000u) ? ~ub : (ub | 0x80000000u);
  uint64_t key = ((uint64_t)tk << 32) | (uint32_t)(e & 4095);

  k64[e]  = key;
  jraw[t] = key;
  __syncthreads();

  int r = 0;
#pragma unroll 8
  for (int uu = 0; uu < CLEN; ++uu) r += (int)(jraw[uu] < key);
  jsrt[r] = key;                            // unique keys -> exact ranks
  __syncthreads();

  ksrt[blockIdx.x * CLEN + t] = jsrt[t];    // coalesced sorted chunk
}

// Kernel 2: block (row = b>>3, ic = b&7) x 512 threads. Stage the row's 32
// sorted chunks (32KB) in LDS; thread owns item i = ic*512+t: rank = sum of
// lower_bound over the 32 chunks; rank>=2048 -> scatter idx+weight.
__global__ __launch_bounds__(512)
void rank_out_kernel(const uint64_t* __restrict__ k64,
                     const uint64_t* __restrict__ ksrt,
                     float* __restrict__ out) {
  __shared__ uint64_t ldsrow[4096];         // 32 KB
  int t   = threadIdx.x;
  int row = blockIdx.x >> 3;
  int ic  = blockIdx.x & 7;

  // stage: stride-512 keeps global coalesced and LDS 2-way-bank-free
  const uint64_t* rowp = ksrt + row * 4096;
#pragma unroll
  for (int q = 0; q < 8; ++q) ldsrow[t + q * 512] = rowp[t + q * 512];

  int i = ic * 512 + t;
  uint64_t ki = k64[row * 4096 + i];        // own (unsorted) key
  __syncthreads();

  const int offs[8] = {63, 31, 15, 7, 3, 1, 0, 0};
  const int incs[8] = {64, 32, 16, 8, 4, 2, 1, 1};

  int rank = 0;
#pragma unroll
  for (int batch = 0; batch < 2; ++batch) { // 2 x 16 searches, step-major
    int pos[16];
#pragma unroll
    for (int m = 0; m < 16; ++m) pos[m] = 0;
    int cbase = batch * 16 * CLEN;
#pragma unroll
    for (int s = 0; s < 8; ++s) {
      uint64_t vv[16];
#pragma unroll
      for (int m = 0; m < 16; ++m) vv[m] = ldsrow[cbase + m * CLEN + pos[m] + offs[s]];
#pragma unroll
      for (int m = 0; m < 16; ++m) pos[m] += (vv[m] < ki) ? incs[s] : 0;
    }
#pragma unroll
    for (int m = 0; m < 16; ++m) rank += pos[m];
  }

  if (rank >= 2048) {
    int j = rank - 2048;
    out[row * 2048 + j] = (float)i;
    out[16384 + row * 2048 + j] = fminf(__fdiv_rn((float)j, 204.8f), 1.0f);
  }
}

extern "C" void kernel_launch(void* const* d_in, const int* in_sizes, int n_in,
                              void* d_out, int out_size, void* d_ws, size_t ws_size,
                              hipStream_t stream) {
  const float* scores = (const float*)d_in[0];
  float* out = (float*)d_out;

  uint64_t* k64  = (uint64_t*)d_ws;                         // 256 KB unsorted
  uint64_t* ksrt = (uint64_t*)d_ws + 32768;                 // 256 KB sorted

  // split(key(42), 3), partitionable layout (verified r1)
  TF2 K1 = threefry2x32(0u, 42u, 0u, 0u);
  TF2 K2 = threefry2x32(0u, 42u, 0u, 1u);
  TF2 K3 = threefry2x32(0u, 42u, 0u, 2u);

  // batch_mask rows on host: uniform(k2,(8,1)) < 0.75
  uint32_t rowmask = 0;
  for (uint32_t b = 0; b < 8; ++b) {
    uint32_t bits = random_bits_at(K2.a, K2.b, b);
    if ((bits >> 9) < 6291456u) rowmask |= (1u << b);
  }

  noise_sort_kernel<<<256, 128, 0, stream>>>(scores, k64, ksrt,
                                             K1.a, K1.b, K3.a, K3.b, rowmask);
  rank_out_kernel<<<64, 512, 0, stream>>>(k64, ksrt, out);
}

// Round 15
// 15.631 us; speedup vs baseline: 1.8569x; 1.1372x over previous
//
#include <hip/hip_runtime.h>
#include <stdint.h>
#include <math.h>

// ---------------------------------------------------------------------------
// SubsetItems, round 15: bit-exact math (absmax 0.0 r1-r14). TWO dispatches.
// Change vs r14 (17.77us): k2 re-grid 64x512 -> 128x256 (2x CU coverage for
// the LDS-search kernel; each block still stages the full 32KB row).
// Fixed-floor hypothesis under test: if gain <0.5us, the remaining ~17us is
// per-replay dispatch overhead + unhideable dep chains (512 waves on 1024
// SIMDs) and we are at the ceiling.
//   k1 noise_sort -> per 128-chunk: noise keys, write k64, LDS rank-sort,
//                    write sorted ksrt.
//   k2 rank_out   -> block (row, ic of 16): stage row's 32 sorted chunks
//                    (32KB) in LDS; 1 item/thread; rank = sum of 32 chunk
//                    lower_bounds (step-major 2x16x8); scatter idx+weight.
// ---------------------------------------------------------------------------

#define NCHUNK 32     // chunks per row
#define CLEN   128    // chunk length

struct TF2 { uint32_t a, b; };

__host__ __device__ inline TF2 threefry2x32(uint32_t k0, uint32_t k1,
                                            uint32_t x0, uint32_t x1) {
  const uint32_t ks2 = k0 ^ k1 ^ 0x1BD11BDAu;
#define TF_ROT(v, d) (uint32_t)(((v) << (d)) | ((v) >> (32 - (d))))
#define TF_RND(r) do { x0 += x1; x1 = TF_ROT(x1, r); x1 ^= x0; } while (0)
  x0 += k0; x1 += k1;
  TF_RND(13); TF_RND(15); TF_RND(26); TF_RND(6);
  x0 += k1; x1 += ks2 + 1u;
  TF_RND(17); TF_RND(29); TF_RND(16); TF_RND(24);
  x0 += ks2; x1 += k0 + 2u;
  TF_RND(13); TF_RND(15); TF_RND(26); TF_RND(6);
  x0 += k0; x1 += k1 + 3u;
  TF_RND(17); TF_RND(29); TF_RND(16); TF_RND(24);
  x0 += k1; x1 += ks2 + 4u;
  TF_RND(13); TF_RND(15); TF_RND(26); TF_RND(6);
  x0 += ks2; x1 += k0 + 5u;
#undef TF_RND
#undef TF_ROT
  return {x0, x1};
}

__host__ __device__ __forceinline__ uint32_t random_bits_at(uint32_t ka, uint32_t kb,
                                                            uint32_t idx) {
  TF2 r = threefry2x32(ka, kb, 0u, idx);
  return r.a ^ r.b;
}

// XLA/CHLO ErfInv f32 (bit-exact, verified r1-r14).
__device__ __forceinline__ float erfinv_f32_xla(float x) {
  float xx = __fmul_rn(x, x);
  float v  = -xx;
  float w;
  if (fabsf(v) < 1e-4f) {
    float t = __fmul_rn(__fadd_rn(__fmul_rn(-0.5f, v), 1.0f), v);
    w = -t;
  } else {
    float t = __fadd_rn(v, 1.0f);
    w = -(float)log((double)t);
  }
  float p;
  if (w < 5.0f) {
    float ww = __fadd_rn(w, -2.5f);
    p = 2.81022636e-08f;
    p = __fadd_rn( 3.43273939e-07f, __fmul_rn(p, ww));
    p = __fadd_rn(-3.5233877e-06f,  __fmul_rn(p, ww));
    p = __fadd_rn(-4.39150654e-06f, __fmul_rn(p, ww));
    p = __fadd_rn( 0.00021858087f,  __fmul_rn(p, ww));
    p = __fadd_rn(-0.00125372503f,  __fmul_rn(p, ww));
    p = __fadd_rn(-0.00417768164f,  __fmul_rn(p, ww));
    p = __fadd_rn( 0.246640727f,    __fmul_rn(p, ww));
    p = __fadd_rn( 1.50140941f,     __fmul_rn(p, ww));
  } else {
    float ww = __fadd_rn(__fsqrt_rn(w), -3.0f);
    p = -0.000200214257f;
    p = __fadd_rn( 0.000100950558f, __fmul_rn(p, ww));
    p = __fadd_rn( 0.00134934322f,  __fmul_rn(p, ww));
    p = __fadd_rn(-0.00367342844f,  __fmul_rn(p, ww));
    p = __fadd_rn( 0.00573950773f,  __fmul_rn(p, ww));
    p = __fadd_rn(-0.0076224613f,   __fmul_rn(p, ww));
    p = __fadd_rn( 0.00943887047f,  __fmul_rn(p, ww));
    p = __fadd_rn( 1.00167406f,     __fmul_rn(p, ww));
    p = __fadd_rn( 2.83297682f,     __fmul_rn(p, ww));
  }
  return __fmul_rn(p, x);
}

// Kernel 1: noise -> keys; write unsorted k64; LDS rank-sort the block's
// 128-key chunk (keys unique -> exact scatter); write sorted ksrt.
__global__ __launch_bounds__(128)
void noise_sort_kernel(const float* __restrict__ scores,
                       uint64_t* __restrict__ k64,
                       uint64_t* __restrict__ ksrt,
                       uint32_t k1a, uint32_t k1b, uint32_t k3a, uint32_t k3b,
                       uint32_t rowmask) {
  __shared__ uint64_t jraw[CLEN];
  __shared__ uint64_t jsrt[CLEN];
  int t = threadIdx.x;
  int e = blockIdx.x * CLEN + t;            // 32768
  int b = e >> 12;

  uint32_t mbits = random_bits_at(k1a, k1b, (uint32_t)e);
  bool mask = ((mbits >> 9) <= 838860u) && ((rowmask >> b) & 1u);

  float s  = scores[e];
  float sf = scores[32767 - e];
  float v  = mask ? fmaxf(s, sf) : s;
  float x  = fminf(fmaxf(v, -1.0f), 1.0f);

  uint32_t nbits = random_bits_at(k3a, k3b, (uint32_t)e);
  float f   = __uint_as_float((nbits >> 9) | 0x3f800000u);
  float f01 = __fadd_rn(f, -1.0f);
  const float lo = __uint_as_float(0xBF7FFFFFu);
  float u = __fadd_rn(__fmul_rn(f01, 2.0f), lo);
  u = fmaxf(lo, u);
  float p    = erfinv_f32_xla(u);
  float nrm  = __fmul_rn(__uint_as_float(0x3FB504F3u), p);
  float nois = __fmul_rn(nrm, 0.0009765625f);
  float xnv  = __fadd_rn(x, nois);

  uint32_t ub = __float_as_uint(xnv);
  uint32_t tk = (ub & 0x80000000u) ? ~ub : (ub | 0x80000000u);
  uint64_t key = ((uint64_t)tk << 32) | (uint32_t)(e & 4095);

  k64[e]  = key;
  jraw[t] = key;
  __syncthreads();

  int r = 0;
#pragma unroll 8
  for (int uu = 0; uu < CLEN; ++uu) r += (int)(jraw[uu] < key);
  jsrt[r] = key;                            // unique keys -> exact ranks
  __syncthreads();

  ksrt[blockIdx.x * CLEN + t] = jsrt[t];    // coalesced sorted chunk
}

// Kernel 2: 128 blocks x 256 threads. Block (row = b>>4, ic = b&15): stage
// the row's 32 sorted chunks (32KB) in LDS; thread owns item i = ic*256+t:
// rank = sum of lower_bound over 32 chunks; rank>=2048 -> scatter.
__global__ __launch_bounds__(256)
void rank_out_kernel(const uint64_t* __restrict__ k64,
                     const uint64_t* __restrict__ ksrt,
                     float* __restrict__ out) {
  __shared__ uint64_t ldsrow[4096];         // 32 KB
  int t   = threadIdx.x;
  int row = blockIdx.x >> 4;
  int ic  = blockIdx.x & 15;

  // stage: stride-256 keeps global coalesced and LDS bank-friendly
  const uint64_t* rowp = ksrt + row * 4096;
#pragma unroll
  for (int q = 0; q < 16; ++q) ldsrow[t + q * 256] = rowp[t + q * 256];

  int i = ic * 256 + t;
  uint64_t ki = k64[row * 4096 + i];        // own (unsorted) key
  __syncthreads();

  const int offs[8] = {63, 31, 15, 7, 3, 1, 0, 0};
  const int incs[8] = {64, 32, 16, 8, 4, 2, 1, 1};

  int rank = 0;
#pragma unroll
  for (int batch = 0; batch < 2; ++batch) { // 2 x 16 searches, step-major
    int pos[16];
#pragma unroll
    for (int m = 0; m < 16; ++m) pos[m] = 0;
    int cbase = batch * 16 * CLEN;
#pragma unroll
    for (int s = 0; s < 8; ++s) {
      uint64_t vv[16];
#pragma unroll
      for (int m = 0; m < 16; ++m) vv[m] = ldsrow[cbase + m * CLEN + pos[m] + offs[s]];
#pragma unroll
      for (int m = 0; m < 16; ++m) pos[m] += (vv[m] < ki) ? incs[s] : 0;
    }
#pragma unroll
    for (int m = 0; m < 16; ++m) rank += pos[m];
  }

  if (rank >= 2048) {
    int j = rank - 2048;
    out[row * 2048 + j] = (float)i;
    out[16384 + row * 2048 + j] = fminf(__fdiv_rn((float)j, 204.8f), 1.0f);
  }
}

extern "C" void kernel_launch(void* const* d_in, const int* in_sizes, int n_in,
                              void* d_out, int out_size, void* d_ws, size_t ws_size,
                              hipStream_t stream) {
  const float* scores = (const float*)d_in[0];
  float* out = (float*)d_out;

  uint64_t* k64  = (uint64_t*)d_ws;                         // 256 KB unsorted
  uint64_t* ksrt = (uint64_t*)d_ws + 32768;                 // 256 KB sorted

  // split(key(42), 3), partitionable layout (verified r1)
  TF2 K1 = threefry2x32(0u, 42u, 0u, 0u);
  TF2 K2 = threefry2x32(0u, 42u, 0u, 1u);
  TF2 K3 = threefry2x32(0u, 42u, 0u, 2u);

  // batch_mask rows on host: uniform(k2,(8,1)) < 0.75
  uint32_t rowmask = 0;
  for (uint32_t b = 0; b < 8; ++b) {
    uint32_t bits = random_bits_at(K2.a, K2.b, b);
    if ((bits >> 9) < 6291456u) rowmask |= (1u << b);
  }

  noise_sort_kernel<<<256, 128, 0, stream>>>(scores, k64, ksrt,
                                             K1.a, K1.b, K3.a, K3.b, rowmask);
  rank_out_kernel<<<128, 256, 0, stream>>>(k64, ksrt, out);
}

// Round 16
// 14.872 us; speedup vs baseline: 1.9516x; 1.0510x over previous
//
#include <hip/hip_runtime.h>
#include <stdint.h>
#include <math.h>

// ---------------------------------------------------------------------------
// SubsetItems, round 16: bit-exact math (absmax 0.0 r1-r15). TWO dispatches.
// Changes vs r15 (15.63us), following the measured gradient (CU-breadth):
//   - k2 re-grid 128x256 -> 256x128 (1 block/CU on all 256 CUs) + ulonglong2
//     staging (16x16B loads/thread).
//   - k1 256x128 -> 256x256 split-count sort: 2 threads/key count 64 compares
//     each (serial chain 128->64), ushort LDS combine; noise math untouched.
//   k1 noise_sort -> per 128-chunk: noise keys, write k64, LDS rank-sort,
//                    write sorted ksrt.
//   k2 rank_out   -> block (row, ic of 32): stage row's 32 sorted chunks
//                    (32KB) in LDS; 1 item/thread; rank = sum of 32 chunk
//                    lower_bounds (step-major 2x16x8); scatter idx+weight.
// ---------------------------------------------------------------------------

#define NCHUNK 32     // chunks per row
#define CLEN   128    // chunk length

struct TF2 { uint32_t a, b; };

__host__ __device__ inline TF2 threefry2x32(uint32_t k0, uint32_t k1,
                                            uint32_t x0, uint32_t x1) {
  const uint32_t ks2 = k0 ^ k1 ^ 0x1BD11BDAu;
#define TF_ROT(v, d) (uint32_t)(((v) << (d)) | ((v) >> (32 - (d))))
#define TF_RND(r) do { x0 += x1; x1 = TF_ROT(x1, r); x1 ^= x0; } while (0)
  x0 += k0; x1 += k1;
  TF_RND(13); TF_RND(15); TF_RND(26); TF_RND(6);
  x0 += k1; x1 += ks2 + 1u;
  TF_RND(17); TF_RND(29); TF_RND(16); TF_RND(24);
  x0 += ks2; x1 += k0 + 2u;
  TF_RND(13); TF_RND(15); TF_RND(26); TF_RND(6);
  x0 += k0; x1 += k1 + 3u;
  TF_RND(17); TF_RND(29); TF_RND(16); TF_RND(24);
  x0 += k1; x1 += ks2 + 4u;
  TF_RND(13); TF_RND(15); TF_RND(26); TF_RND(6);
  x0 += ks2; x1 += k0 + 5u;
#undef TF_RND
#undef TF_ROT
  return {x0, x1};
}

__host__ __device__ __forceinline__ uint32_t random_bits_at(uint32_t ka, uint32_t kb,
                                                            uint32_t idx) {
  TF2 r = threefry2x32(ka, kb, 0u, idx);
  return r.a ^ r.b;
}

// XLA/CHLO ErfInv f32 (bit-exact, verified r1-r15).
__device__ __forceinline__ float erfinv_f32_xla(float x) {
  float xx = __fmul_rn(x, x);
  float v  = -xx;
  float w;
  if (fabsf(v) < 1e-4f) {
    float t = __fmul_rn(__fadd_rn(__fmul_rn(-0.5f, v), 1.0f), v);
    w = -t;
  } else {
    float t = __fadd_rn(v, 1.0f);
    w = -(float)log((double)t);
  }
  float p;
  if (w < 5.0f) {
    float ww = __fadd_rn(w, -2.5f);
    p = 2.81022636e-08f;
    p = __fadd_rn( 3.43273939e-07f, __fmul_rn(p, ww));
    p = __fadd_rn(-3.5233877e-06f,  __fmul_rn(p, ww));
    p = __fadd_rn(-4.39150654e-06f, __fmul_rn(p, ww));
    p = __fadd_rn( 0.00021858087f,  __fmul_rn(p, ww));
    p = __fadd_rn(-0.00125372503f,  __fmul_rn(p, ww));
    p = __fadd_rn(-0.00417768164f,  __fmul_rn(p, ww));
    p = __fadd_rn( 0.246640727f,    __fmul_rn(p, ww));
    p = __fadd_rn( 1.50140941f,     __fmul_rn(p, ww));
  } else {
    float ww = __fadd_rn(__fsqrt_rn(w), -3.0f);
    p = -0.000200214257f;
    p = __fadd_rn( 0.000100950558f, __fmul_rn(p, ww));
    p = __fadd_rn( 0.00134934322f,  __fmul_rn(p, ww));
    p = __fadd_rn(-0.00367342844f,  __fmul_rn(p, ww));
    p = __fadd_rn( 0.00573950773f,  __fmul_rn(p, ww));
    p = __fadd_rn(-0.0076224613f,   __fmul_rn(p, ww));
    p = __fadd_rn( 0.00943887047f,  __fmul_rn(p, ww));
    p = __fadd_rn( 1.00167406f,     __fmul_rn(p, ww));
    p = __fadd_rn( 2.83297682f,     __fmul_rn(p, ww));
  }
  return __fmul_rn(p, x);
}

// Kernel 1: 256 blocks x 256 threads, one 128-elem chunk per block.
// Threads t<128: noise -> key, write k64, stash in LDS. All 256 threads:
// split-count sort (key k=t&127, half h=t>>7 counts 64 compares), ushort
// combine, scatter jsrt (keys unique -> exact), write sorted ksrt.
__global__ __launch_bounds__(256)
void noise_sort_kernel(const float* __restrict__ scores,
                       uint64_t* __restrict__ k64,
                       uint64_t* __restrict__ ksrt,
                       uint32_t k1a, uint32_t k1b, uint32_t k3a, uint32_t k3b,
                       uint32_t rowmask) {
  __shared__ uint64_t jraw[CLEN];
  __shared__ uint64_t jsrt[CLEN];
  __shared__ unsigned short scnt[2][CLEN];
  int t = threadIdx.x;                      // 0..255
  int kk = t & 127, h = t >> 7;

  if (t < CLEN) {
    int e = blockIdx.x * CLEN + t;          // 32768
    int b = e >> 12;

    uint32_t mbits = random_bits_at(k1a, k1b, (uint32_t)e);
    bool mask = ((mbits >> 9) <= 838860u) && ((rowmask >> b) & 1u);

    float s  = scores[e];
    float sf = scores[32767 - e];
    float v  = mask ? fmaxf(s, sf) : s;
    float x  = fminf(fmaxf(v, -1.0f), 1.0f);

    uint32_t nbits = random_bits_at(k3a, k3b, (uint32_t)e);
    float f   = __uint_as_float((nbits >> 9) | 0x3f800000u);
    float f01 = __fadd_rn(f, -1.0f);
    const float lo = __uint_as_float(0xBF7FFFFFu);
    float u = __fadd_rn(__fmul_rn(f01, 2.0f), lo);
    u = fmaxf(lo, u);
    float p    = erfinv_f32_xla(u);
    float nrm  = __fmul_rn(__uint_as_float(0x3FB504F3u), p);
    float nois = __fmul_rn(nrm, 0.0009765625f);
    float xnv  = __fadd_rn(x, nois);

    uint32_t ub = __float_as_uint(xnv);
    uint32_t tk = (ub & 0x80000000u) ? ~ub : (ub | 0x80000000u);
    uint64_t key = ((uint64_t)tk << 32) | (uint32_t)(e & 4095);

    k64[e]  = key;
    jraw[t] = key;
  }
  __syncthreads();

  // split count: half h compares its key against jraw[h*64 .. h*64+63]
  {
    uint64_t mykey = jraw[kk];
    int r = 0;
    const uint64_t* half = jraw + h * 64;
#pragma unroll 8
    for (int uu = 0; uu < 64; ++uu) r += (int)(half[uu] < mykey);
    scnt[h][kk] = (unsigned short)r;
  }
  __syncthreads();

  if (t < CLEN) {
    int r = (int)scnt[0][t] + (int)scnt[1][t];
    jsrt[r] = jraw[t];                      // unique keys -> exact ranks
  }
  __syncthreads();

  if (t < CLEN) ksrt[blockIdx.x * CLEN + t] = jsrt[t];
}

// Kernel 2: 256 blocks x 128 threads (1 block/CU). Block (row = b>>5,
// ic = b&31): stage the row's 32 sorted chunks (32KB) via ulonglong2; thread
// owns item i = ic*128+t: rank = sum of lower_bound over 32 chunks
// (step-major 2x16x8); rank>=2048 -> scatter idx+weight.
__global__ __launch_bounds__(128)
void rank_out_kernel(const uint64_t* __restrict__ k64,
                     const uint64_t* __restrict__ ksrt,
                     float* __restrict__ out) {
  __shared__ uint64_t ldsrow[4096];         // 32 KB
  int t   = threadIdx.x;                    // 0..127
  int row = blockIdx.x >> 5;
  int ic  = blockIdx.x & 31;

  const ulonglong2* rowp2 = (const ulonglong2*)(ksrt + row * 4096);
#pragma unroll
  for (int q = 0; q < 16; ++q) {
    ulonglong2 v = rowp2[t + q * 128];
    ldsrow[2 * (t + q * 128)]     = v.x;
    ldsrow[2 * (t + q * 128) + 1] = v.y;
  }

  int i = ic * 128 + t;
  uint64_t ki = k64[row * 4096 + i];        // own (unsorted) key
  __syncthreads();

  const int offs[8] = {63, 31, 15, 7, 3, 1, 0, 0};
  const int incs[8] = {64, 32, 16, 8, 4, 2, 1, 1};

  int rank = 0;
#pragma unroll
  for (int batch = 0; batch < 2; ++batch) { // 2 x 16 searches, step-major
    int pos[16];
#pragma unroll
    for (int m = 0; m < 16; ++m) pos[m] = 0;
    int cbase = batch * 16 * CLEN;
#pragma unroll
    for (int s = 0; s < 8; ++s) {
      uint64_t vv[16];
#pragma unroll
      for (int m = 0; m < 16; ++m) vv[m] = ldsrow[cbase + m * CLEN + pos[m] + offs[s]];
#pragma unroll
      for (int m = 0; m < 16; ++m) pos[m] += (vv[m] < ki) ? incs[s] : 0;
    }
#pragma unroll
    for (int m = 0; m < 16; ++m) rank += pos[m];
  }

  if (rank >= 2048) {
    int j = rank - 2048;
    out[row * 2048 + j] = (float)i;
    out[16384 + row * 2048 + j] = fminf(__fdiv_rn((float)j, 204.8f), 1.0f);
  }
}

extern "C" void kernel_launch(void* const* d_in, const int* in_sizes, int n_in,
                              void* d_out, int out_size, void* d_ws, size_t ws_size,
                              hipStream_t stream) {
  const float* scores = (const float*)d_in[0];
  float* out = (float*)d_out;

  uint64_t* k64  = (uint64_t*)d_ws;                         // 256 KB unsorted
  uint64_t* ksrt = (uint64_t*)d_ws + 32768;                 // 256 KB sorted

  // split(key(42), 3), partitionable layout (verified r1)
  TF2 K1 = threefry2x32(0u, 42u, 0u, 0u);
  TF2 K2 = threefry2x32(0u, 42u, 0u, 1u);
  TF2 K3 = threefry2x32(0u, 42u, 0u, 2u);

  // batch_mask rows on host: uniform(k2,(8,1)) < 0.75
  uint32_t rowmask = 0;
  for (uint32_t b = 0; b < 8; ++b) {
    uint32_t bits = random_bits_at(K2.a, K2.b, b);
    if ((bits >> 9) < 6291456u) rowmask |= (1u << b);
  }

  noise_sort_kernel<<<256, 256, 0, stream>>>(scores, k64, ksrt,
                                             K1.a, K1.b, K3.a, K3.b, rowmask);
  rank_out_kernel<<<256, 128, 0, stream>>>(k64, ksrt, out);
}

// Round 17
// 14.310 us; speedup vs baseline: 2.0282x; 1.0393x over previous
//
#include <hip/hip_runtime.h>
#include <stdint.h>
#include <math.h>

// ---------------------------------------------------------------------------
// SubsetItems, round 17: bit-exact math (absmax 0.0 r1-r16). TWO dispatches.
// Changes vs r16 (14.87us), continuing the chain-split/CU-breadth gradient:
//   - k2: 512 blocks x 128 thr, 2 threads/item (halves h=0/1 search chunks
//     16h..16h+15): per-thread search = ONE 16-wide step-major batch x 8
//     dependent steps (was 2 sequential batches); LDS combine; t<64 scatters.
//   - k1: 256 blocks x 512 thr, 4-way split-count sort (32 compares/thread,
//     chain 64->32), ushort scnt[4][128] combine. Noise math untouched.
// ---------------------------------------------------------------------------

#define NCHUNK 32     // chunks per row
#define CLEN   128    // chunk length

struct TF2 { uint32_t a, b; };

__host__ __device__ inline TF2 threefry2x32(uint32_t k0, uint32_t k1,
                                            uint32_t x0, uint32_t x1) {
  const uint32_t ks2 = k0 ^ k1 ^ 0x1BD11BDAu;
#define TF_ROT(v, d) (uint32_t)(((v) << (d)) | ((v) >> (32 - (d))))
#define TF_RND(r) do { x0 += x1; x1 = TF_ROT(x1, r); x1 ^= x0; } while (0)
  x0 += k0; x1 += k1;
  TF_RND(13); TF_RND(15); TF_RND(26); TF_RND(6);
  x0 += k1; x1 += ks2 + 1u;
  TF_RND(17); TF_RND(29); TF_RND(16); TF_RND(24);
  x0 += ks2; x1 += k0 + 2u;
  TF_RND(13); TF_RND(15); TF_RND(26); TF_RND(6);
  x0 += k0; x1 += k1 + 3u;
  TF_RND(17); TF_RND(29); TF_RND(16); TF_RND(24);
  x0 += k1; x1 += ks2 + 4u;
  TF_RND(13); TF_RND(15); TF_RND(26); TF_RND(6);
  x0 += ks2; x1 += k0 + 5u;
#undef TF_RND
#undef TF_ROT
  return {x0, x1};
}

__host__ __device__ __forceinline__ uint32_t random_bits_at(uint32_t ka, uint32_t kb,
                                                            uint32_t idx) {
  TF2 r = threefry2x32(ka, kb, 0u, idx);
  return r.a ^ r.b;
}

// XLA/CHLO ErfInv f32 (bit-exact, verified r1-r16).
__device__ __forceinline__ float erfinv_f32_xla(float x) {
  float xx = __fmul_rn(x, x);
  float v  = -xx;
  float w;
  if (fabsf(v) < 1e-4f) {
    float t = __fmul_rn(__fadd_rn(__fmul_rn(-0.5f, v), 1.0f), v);
    w = -t;
  } else {
    float t = __fadd_rn(v, 1.0f);
    w = -(float)log((double)t);
  }
  float p;
  if (w < 5.0f) {
    float ww = __fadd_rn(w, -2.5f);
    p = 2.81022636e-08f;
    p = __fadd_rn( 3.43273939e-07f, __fmul_rn(p, ww));
    p = __fadd_rn(-3.5233877e-06f,  __fmul_rn(p, ww));
    p = __fadd_rn(-4.39150654e-06f, __fmul_rn(p, ww));
    p = __fadd_rn( 0.00021858087f,  __fmul_rn(p, ww));
    p = __fadd_rn(-0.00125372503f,  __fmul_rn(p, ww));
    p = __fadd_rn(-0.00417768164f,  __fmul_rn(p, ww));
    p = __fadd_rn( 0.246640727f,    __fmul_rn(p, ww));
    p = __fadd_rn( 1.50140941f,     __fmul_rn(p, ww));
  } else {
    float ww = __fadd_rn(__fsqrt_rn(w), -3.0f);
    p = -0.000200214257f;
    p = __fadd_rn( 0.000100950558f, __fmul_rn(p, ww));
    p = __fadd_rn( 0.00134934322f,  __fmul_rn(p, ww));
    p = __fadd_rn(-0.00367342844f,  __fmul_rn(p, ww));
    p = __fadd_rn( 0.00573950773f,  __fmul_rn(p, ww));
    p = __fadd_rn(-0.0076224613f,   __fmul_rn(p, ww));
    p = __fadd_rn( 0.00943887047f,  __fmul_rn(p, ww));
    p = __fadd_rn( 1.00167406f,     __fmul_rn(p, ww));
    p = __fadd_rn( 2.83297682f,     __fmul_rn(p, ww));
  }
  return __fmul_rn(p, x);
}

// Kernel 1: 256 blocks x 512 threads, one 128-elem chunk per block.
// t<128: noise -> key, write k64, stash LDS. All: 4-way split-count sort
// (key kk=t&127, quarter h=t>>7 counts 32 compares), ushort combine,
// scatter jsrt (keys unique -> exact), write sorted ksrt.
__global__ __launch_bounds__(512)
void noise_sort_kernel(const float* __restrict__ scores,
                       uint64_t* __restrict__ k64,
                       uint64_t* __restrict__ ksrt,
                       uint32_t k1a, uint32_t k1b, uint32_t k3a, uint32_t k3b,
                       uint32_t rowmask) {
  __shared__ uint64_t jraw[CLEN];
  __shared__ uint64_t jsrt[CLEN];
  __shared__ unsigned short scnt[4][CLEN];
  int t = threadIdx.x;                      // 0..511
  int kk = t & 127, h = t >> 7;             // h = 0..3

  if (t < CLEN) {
    int e = blockIdx.x * CLEN + t;          // 32768
    int b = e >> 12;

    uint32_t mbits = random_bits_at(k1a, k1b, (uint32_t)e);
    bool mask = ((mbits >> 9) <= 838860u) && ((rowmask >> b) & 1u);

    float s  = scores[e];
    float sf = scores[32767 - e];
    float v  = mask ? fmaxf(s, sf) : s;
    float x  = fminf(fmaxf(v, -1.0f), 1.0f);

    uint32_t nbits = random_bits_at(k3a, k3b, (uint32_t)e);
    float f   = __uint_as_float((nbits >> 9) | 0x3f800000u);
    float f01 = __fadd_rn(f, -1.0f);
    const float lo = __uint_as_float(0xBF7FFFFFu);
    float u = __fadd_rn(__fmul_rn(f01, 2.0f), lo);
    u = fmaxf(lo, u);
    float p    = erfinv_f32_xla(u);
    float nrm  = __fmul_rn(__uint_as_float(0x3FB504F3u), p);
    float nois = __fmul_rn(nrm, 0.0009765625f);
    float xnv  = __fadd_rn(x, nois);

    uint32_t ub = __float_as_uint(xnv);
    uint32_t tk = (ub & 0x80000000u) ? ~ub : (ub | 0x80000000u);
    uint64_t key = ((uint64_t)tk << 32) | (uint32_t)(e & 4095);

    k64[e]  = key;
    jraw[t] = key;
  }
  __syncthreads();

  // split count: quarter h compares its key against jraw[h*32 .. h*32+31]
  {
    uint64_t mykey = jraw[kk];
    int r = 0;
    const uint64_t* quart = jraw + h * 32;
#pragma unroll 8
    for (int uu = 0; uu < 32; ++uu) r += (int)(quart[uu] < mykey);
    scnt[h][kk] = (unsigned short)r;
  }
  __syncthreads();

  if (t < CLEN) {
    int r = (int)scnt[0][t] + (int)scnt[1][t] + (int)scnt[2][t] + (int)scnt[3][t];
    jsrt[r] = jraw[t];                      // unique keys -> exact ranks
  }
  __syncthreads();

  if (t < CLEN) ksrt[blockIdx.x * CLEN + t] = jsrt[t];
}

// Kernel 2: 512 blocks x 128 threads. Block (row = b>>6, ic = b&63) owns 64
// items; 2 threads/item (half hh searches chunks 16hh..16hh+15, ONE 16-wide
// step-major batch x 8 steps); LDS combine; t<64 scatters idx+weight.
__global__ __launch_bounds__(128)
void rank_out_kernel(const uint64_t* __restrict__ k64,
                     const uint64_t* __restrict__ ksrt,
                     float* __restrict__ out) {
  __shared__ uint64_t ldsrow[4096];         // 32 KB
  __shared__ int prank[2][64];
  int t   = threadIdx.x;                    // 0..127
  int row = blockIdx.x >> 6;
  int ic  = blockIdx.x & 63;

  const ulonglong2* rowp2 = (const ulonglong2*)(ksrt + row * 4096);
#pragma unroll
  for (int q = 0; q < 16; ++q) {
    ulonglong2 v = rowp2[t + q * 128];
    ldsrow[2 * (t + q * 128)]     = v.x;
    ldsrow[2 * (t + q * 128) + 1] = v.y;
  }

  int it = t & 63, hh = t >> 6;             // item slot, chunk-half
  int i  = ic * 64 + it;
  uint64_t ki = k64[row * 4096 + i];        // own (unsorted) key
  __syncthreads();

  const int offs[8] = {63, 31, 15, 7, 3, 1, 0, 0};
  const int incs[8] = {64, 32, 16, 8, 4, 2, 1, 1};

  int pos[16];
#pragma unroll
  for (int m = 0; m < 16; ++m) pos[m] = 0;
  int cbase = hh * 16 * CLEN;
#pragma unroll
  for (int s = 0; s < 8; ++s) {
    uint64_t vv[16];
#pragma unroll
    for (int m = 0; m < 16; ++m) vv[m] = ldsrow[cbase + m * CLEN + pos[m] + offs[s]];
#pragma unroll
    for (int m = 0; m < 16; ++m) pos[m] += (vv[m] < ki) ? incs[s] : 0;
  }
  int r = 0;
#pragma unroll
  for (int m = 0; m < 16; ++m) r += pos[m];
  prank[hh][it] = r;
  __syncthreads();

  if (t < 64) {
    int rank = prank[0][t] + prank[1][t];
    if (rank >= 2048) {
      int j = rank - 2048;
      int i2 = ic * 64 + t;
      out[row * 2048 + j] = (float)i2;
      out[16384 + row * 2048 + j] = fminf(__fdiv_rn((float)j, 204.8f), 1.0f);
    }
  }
}

extern "C" void kernel_launch(void* const* d_in, const int* in_sizes, int n_in,
                              void* d_out, int out_size, void* d_ws, size_t ws_size,
                              hipStream_t stream) {
  const float* scores = (const float*)d_in[0];
  float* out = (float*)d_out;

  uint64_t* k64  = (uint64_t*)d_ws;                         // 256 KB unsorted
  uint64_t* ksrt = (uint64_t*)d_ws + 32768;                 // 256 KB sorted

  // split(key(42), 3), partitionable layout (verified r1)
  TF2 K1 = threefry2x32(0u, 42u, 0u, 0u);
  TF2 K2 = threefry2x32(0u, 42u, 0u, 1u);
  TF2 K3 = threefry2x32(0u, 42u, 0u, 2u);

  // batch_mask rows on host: uniform(k2,(8,1)) < 0.75
  uint32_t rowmask = 0;
  for (uint32_t b = 0; b < 8; ++b) {
    uint32_t bits = random_bits_at(K2.a, K2.b, b);
    if ((bits >> 9) < 6291456u) rowmask |= (1u << b);
  }

  noise_sort_kernel<<<256, 512, 0, stream>>>(scores, k64, ksrt,
                                             K1.a, K1.b, K3.a, K3.b, rowmask);
  rank_out_kernel<<<512, 128, 0, stream>>>(k64, ksrt, out);
}

// Round 18
// 13.704 us; speedup vs baseline: 2.1179x; 1.0442x over previous
//
#include <hip/hip_runtime.h>
#include <stdint.h>
#include <math.h>

// ---------------------------------------------------------------------------
// SubsetItems, round 18: bit-exact math (absmax 0.0 r1-r17). TWO dispatches.
// Changes vs r17 (14.31us), last rungs of the chain-split gradient:
//   - k1: noise split across wave pairs — t<128 runs the LONG chain (noise
//     threefry + erfinv + f64 log), 128<=t<256 runs the SHORT chain (mask
//     threefry + flip-max + clip) -> phase wall = max, not sum; combine via
//     LDS; then 4-way split-count sort (r17 scheme, unchanged).
//   - k2: 512 blocks x 256 thr, 4 threads/item (quarter hh searches chunks
//     8hh..8hh+7, ONE 8-wide step-major batch x 8 steps); 8 waves/CU.
// ---------------------------------------------------------------------------

#define NCHUNK 32     // chunks per row
#define CLEN   128    // chunk length

struct TF2 { uint32_t a, b; };

__host__ __device__ inline TF2 threefry2x32(uint32_t k0, uint32_t k1,
                                            uint32_t x0, uint32_t x1) {
  const uint32_t ks2 = k0 ^ k1 ^ 0x1BD11BDAu;
#define TF_ROT(v, d) (uint32_t)(((v) << (d)) | ((v) >> (32 - (d))))
#define TF_RND(r) do { x0 += x1; x1 = TF_ROT(x1, r); x1 ^= x0; } while (0)
  x0 += k0; x1 += k1;
  TF_RND(13); TF_RND(15); TF_RND(26); TF_RND(6);
  x0 += k1; x1 += ks2 + 1u;
  TF_RND(17); TF_RND(29); TF_RND(16); TF_RND(24);
  x0 += ks2; x1 += k0 + 2u;
  TF_RND(13); TF_RND(15); TF_RND(26); TF_RND(6);
  x0 += k0; x1 += k1 + 3u;
  TF_RND(17); TF_RND(29); TF_RND(16); TF_RND(24);
  x0 += k1; x1 += ks2 + 4u;
  TF_RND(13); TF_RND(15); TF_RND(26); TF_RND(6);
  x0 += ks2; x1 += k0 + 5u;
#undef TF_RND
#undef TF_ROT
  return {x0, x1};
}

__host__ __device__ __forceinline__ uint32_t random_bits_at(uint32_t ka, uint32_t kb,
                                                            uint32_t idx) {
  TF2 r = threefry2x32(ka, kb, 0u, idx);
  return r.a ^ r.b;
}

// XLA/CHLO ErfInv f32 (bit-exact, verified r1-r17).
__device__ __forceinline__ float erfinv_f32_xla(float x) {
  float xx = __fmul_rn(x, x);
  float v  = -xx;
  float w;
  if (fabsf(v) < 1e-4f) {
    float t = __fmul_rn(__fadd_rn(__fmul_rn(-0.5f, v), 1.0f), v);
    w = -t;
  } else {
    float t = __fadd_rn(v, 1.0f);
    w = -(float)log((double)t);
  }
  float p;
  if (w < 5.0f) {
    float ww = __fadd_rn(w, -2.5f);
    p = 2.81022636e-08f;
    p = __fadd_rn( 3.43273939e-07f, __fmul_rn(p, ww));
    p = __fadd_rn(-3.5233877e-06f,  __fmul_rn(p, ww));
    p = __fadd_rn(-4.39150654e-06f, __fmul_rn(p, ww));
    p = __fadd_rn( 0.00021858087f,  __fmul_rn(p, ww));
    p = __fadd_rn(-0.00125372503f,  __fmul_rn(p, ww));
    p = __fadd_rn(-0.00417768164f,  __fmul_rn(p, ww));
    p = __fadd_rn( 0.246640727f,    __fmul_rn(p, ww));
    p = __fadd_rn( 1.50140941f,     __fmul_rn(p, ww));
  } else {
    float ww = __fadd_rn(__fsqrt_rn(w), -3.0f);
    p = -0.000200214257f;
    p = __fadd_rn( 0.000100950558f, __fmul_rn(p, ww));
    p = __fadd_rn( 0.00134934322f,  __fmul_rn(p, ww));
    p = __fadd_rn(-0.00367342844f,  __fmul_rn(p, ww));
    p = __fadd_rn( 0.00573950773f,  __fmul_rn(p, ww));
    p = __fadd_rn(-0.0076224613f,   __fmul_rn(p, ww));
    p = __fadd_rn( 0.00943887047f,  __fmul_rn(p, ww));
    p = __fadd_rn( 1.00167406f,     __fmul_rn(p, ww));
    p = __fadd_rn( 2.83297682f,     __fmul_rn(p, ww));
  }
  return __fmul_rn(p, x);
}

// Kernel 1: 256 blocks x 512 threads, one 128-elem chunk per block.
// Phase A (parallel chains): t<128 computes the LONG chain (noise bits ->
// erfinv -> nois); 128<=t<256 computes the SHORT chain (mask bits -> clip x)
// into LDS. Combine: t<128 forms key, writes k64 + jraw.
// Phase B: 4-way split-count sort (quarter h counts 32 compares), scatter.
__global__ __launch_bounds__(512)
void noise_sort_kernel(const float* __restrict__ scores,
                       uint64_t* __restrict__ k64,
                       uint64_t* __restrict__ ksrt,
                       uint32_t k1a, uint32_t k1b, uint32_t k3a, uint32_t k3b,
                       uint32_t rowmask) {
  __shared__ uint64_t jraw[CLEN];
  __shared__ uint64_t jsrt[CLEN];
  __shared__ float    xsh[CLEN];
  __shared__ unsigned short scnt[4][CLEN];
  int t = threadIdx.x;                      // 0..511
  int kk = t & 127, h = t >> 7;             // h = 0..3

  float nois = 0.0f;
  if (t < CLEN) {
    // LONG chain: noise bits -> erfinv -> nois  (element e = blk*128 + t)
    int e = blockIdx.x * CLEN + t;
    uint32_t nbits = random_bits_at(k3a, k3b, (uint32_t)e);
    float f   = __uint_as_float((nbits >> 9) | 0x3f800000u);
    float f01 = __fadd_rn(f, -1.0f);
    const float lo = __uint_as_float(0xBF7FFFFFu);
    float u = __fadd_rn(__fmul_rn(f01, 2.0f), lo);
    u = fmaxf(lo, u);
    float p    = erfinv_f32_xla(u);
    float nrm  = __fmul_rn(__uint_as_float(0x3FB504F3u), p);
    nois = __fmul_rn(nrm, 0.0009765625f);
  } else if (t < 2 * CLEN) {
    // SHORT chain: mask bits -> flip-max -> clip  (element e2 for lane t-128)
    int e2 = blockIdx.x * CLEN + (t - CLEN);
    int b  = e2 >> 12;
    uint32_t mbits = random_bits_at(k1a, k1b, (uint32_t)e2);
    bool mask = ((mbits >> 9) <= 838860u) && ((rowmask >> b) & 1u);
    float s  = scores[e2];
    float sf = scores[32767 - e2];
    float v  = mask ? fmaxf(s, sf) : s;
    xsh[t - CLEN] = fminf(fmaxf(v, -1.0f), 1.0f);
  }
  __syncthreads();

  if (t < CLEN) {
    int e = blockIdx.x * CLEN + t;
    float xnv = __fadd_rn(xsh[t], nois);
    uint32_t ub = __float_as_uint(xnv);
    uint32_t tk = (ub & 0x80000000u) ? ~ub : (ub | 0x80000000u);
    uint64_t key = ((uint64_t)tk << 32) | (uint32_t)(e & 4095);
    k64[e]  = key;
    jraw[t] = key;
  }
  __syncthreads();

  // split count: quarter h compares its key against jraw[h*32 .. h*32+31]
  {
    uint64_t mykey = jraw[kk];
    int r = 0;
    const uint64_t* quart = jraw + h * 32;
#pragma unroll 8
    for (int uu = 0; uu < 32; ++uu) r += (int)(quart[uu] < mykey);
    scnt[h][kk] = (unsigned short)r;
  }
  __syncthreads();

  if (t < CLEN) {
    int r = (int)scnt[0][t] + (int)scnt[1][t] + (int)scnt[2][t] + (int)scnt[3][t];
    jsrt[r] = jraw[t];                      // unique keys -> exact ranks
  }
  __syncthreads();

  if (t < CLEN) ksrt[blockIdx.x * CLEN + t] = jsrt[t];
}

// Kernel 2: 512 blocks x 256 threads (2 blocks/CU, 8 waves/CU). Block
// (row = b>>6, ic = b&63) owns 64 items; 4 threads/item (quarter hh searches
// chunks 8hh..8hh+7, ONE 8-wide step-major batch x 8 steps); LDS combine;
// t<64 scatters idx+weight.
__global__ __launch_bounds__(256)
void rank_out_kernel(const uint64_t* __restrict__ k64,
                     const uint64_t* __restrict__ ksrt,
                     float* __restrict__ out) {
  __shared__ uint64_t ldsrow[4096];         // 32 KB
  __shared__ int prank[4][64];
  int t   = threadIdx.x;                    // 0..255
  int row = blockIdx.x >> 6;
  int ic  = blockIdx.x & 63;

  const ulonglong2* rowp2 = (const ulonglong2*)(ksrt + row * 4096);
#pragma unroll
  for (int q = 0; q < 8; ++q) {
    ulonglong2 v = rowp2[t + q * 256];
    ldsrow[2 * (t + q * 256)]     = v.x;
    ldsrow[2 * (t + q * 256) + 1] = v.y;
  }

  int it = t & 63, hh = t >> 6;             // item slot, chunk-quarter 0..3
  int i  = ic * 64 + it;
  uint64_t ki = k64[row * 4096 + i];        // own (unsorted) key
  __syncthreads();

  const int offs[8] = {63, 31, 15, 7, 3, 1, 0, 0};
  const int incs[8] = {64, 32, 16, 8, 4, 2, 1, 1};

  int pos[8];
#pragma unroll
  for (int m = 0; m < 8; ++m) pos[m] = 0;
  int cbase = hh * 8 * CLEN;
#pragma unroll
  for (int s = 0; s < 8; ++s) {
    uint64_t vv[8];
#pragma unroll
    for (int m = 0; m < 8; ++m) vv[m] = ldsrow[cbase + m * CLEN + pos[m] + offs[s]];
#pragma unroll
    for (int m = 0; m < 8; ++m) pos[m] += (vv[m] < ki) ? incs[s] : 0;
  }
  int r = 0;
#pragma unroll
  for (int m = 0; m < 8; ++m) r += pos[m];
  prank[hh][it] = r;
  __syncthreads();

  if (t < 64) {
    int rank = prank[0][t] + prank[1][t] + prank[2][t] + prank[3][t];
    if (rank >= 2048) {
      int j = rank - 2048;
      int i2 = ic * 64 + t;
      out[row * 2048 + j] = (float)i2;
      out[16384 + row * 2048 + j] = fminf(__fdiv_rn((float)j, 204.8f), 1.0f);
    }
  }
}

extern "C" void kernel_launch(void* const* d_in, const int* in_sizes, int n_in,
                              void* d_out, int out_size, void* d_ws, size_t ws_size,
                              hipStream_t stream) {
  const float* scores = (const float*)d_in[0];
  float* out = (float*)d_out;

  uint64_t* k64  = (uint64_t*)d_ws;                         // 256 KB unsorted
  uint64_t* ksrt = (uint64_t*)d_ws + 32768;                 // 256 KB sorted

  // split(key(42), 3), partitionable layout (verified r1)
  TF2 K1 = threefry2x32(0u, 42u, 0u, 0u);
  TF2 K2 = threefry2x32(0u, 42u, 0u, 1u);
  TF2 K3 = threefry2x32(0u, 42u, 0u, 2u);

  // batch_mask rows on host: uniform(k2,(8,1)) < 0.75
  uint32_t rowmask = 0;
  for (uint32_t b = 0; b < 8; ++b) {
    uint32_t bits = random_bits_at(K2.a, K2.b, b);
    if ((bits >> 9) < 6291456u) rowmask |= (1u << b);
  }

  noise_sort_kernel<<<256, 512, 0, stream>>>(scores, k64, ksrt,
                                             K1.a, K1.b, K3.a, K3.b, rowmask);
  rank_out_kernel<<<512, 256, 0, stream>>>(k64, ksrt, out);
}